// Round 5
// baseline (873.864 us; speedup 1.0000x reference)
//
#include <hip/hip_runtime.h>
#include <hip/hip_bf16.h>
#include <cfloat>
#include <math.h>

typedef __bf16 bf16;
typedef __bf16 bf16x4 __attribute__((ext_vector_type(4)));
typedef __bf16 bf16x8 __attribute__((ext_vector_type(8)));
typedef float  floatx4 __attribute__((ext_vector_type(4)));
typedef float  floatx2 __attribute__((ext_vector_type(2)));

#define SEQ 2048
#define DM  1024
#define NP  2048
#define CAP (1 << 20)
#define MARGIN 0.5f

// ---------------- mask dtype detect + expand to int[2048] ----------------
__global__ __launch_bounds__(256) void mask_prep(const void* __restrict__ mraw,
                                                 int* __restrict__ maskw) {
  __shared__ int flags;
  int t = threadIdx.x;
  if (t == 0) flags = 0;
  __syncthreads();
  const unsigned short* u16 = (const unsigned short*)mraw;
  const unsigned* u32 = (const unsigned*)mraw;
  int f = 0;
  for (int i = t; i < 1024; i += 256) {
    unsigned short v = u16[i];
    if (v != 0 && v != 0x3F80u) f |= 1;
    if ((i & 1) == 0 && v == 0x3F80u) f |= 2;
  }
  for (int i = t; i < 512; i += 256)
    if (u32[i] > 1u) f |= 4;
  if (f) atomicOr(&flags, f);
  __syncthreads();
  int fl = flags;
  int mode;
  if (!(fl & 1)) mode = (fl & 2) ? 2 : 3;
  else           mode = (fl & 4) ? 1 : 0;
  for (int s = t; s < SEQ; s += 256) {
    int m;
    if (mode == 0)      m = (((const int*)mraw)[s] != 0);
    else if (mode == 1) m = (((const unsigned char*)mraw)[s] != 0);
    else if (mode == 2) m = (u16[s] != 0);
    else                m = (((const float*)mraw)[s] != 0.0f);
    maskw[s] = m;
  }
}

// ---------------- Q/K projection, fp64 VALU, NO LDS ----------
// 128x128 block tile, 8x8 per thread. A-reads: 4 distinct addrs/instr
// (g-groups, L1 broadcast); B-reads: 16 consecutive floats = 1 cacheline
// (broadcast x4). Ascending-k fp64 FMA chain == round-2/4 PASS numerics.
// Also emits bf16 copies of Q/K for the scores kernel.
__global__ __launch_bounds__(256, 2) void proj_qk(
    const float* __restrict__ X,
    const float* __restrict__ Wq, const float* __restrict__ Wk,
    const float* __restrict__ bq, const float* __restrict__ bk,
    float* __restrict__ qo, float* __restrict__ ko,
    bf16* __restrict__ qbo, bf16* __restrict__ kbo) {
  int z = blockIdx.z;
  const float* W   = z ? Wk : Wq;
  const float* bia = z ? bk : bq;
  float*       out = z ? ko : qo;
  bf16*        outb= z ? kbo: qbo;
  int m0 = blockIdx.x * 128, n0 = blockIdx.y * 128;
  int t = threadIdx.x;
  int g = t >> 4, tn = t & 15;
  const float* xr[8];
  #pragma unroll
  for (int i = 0; i < 8; i++) xr[i] = X + (size_t)(m0 + g + 16 * i) * DM;
  const float* wr = W + n0 + tn;
  double acc[8][8];
  #pragma unroll
  for (int i = 0; i < 8; i++)
    #pragma unroll
    for (int j = 0; j < 8; j++) acc[i][j] = 0.0;

  #pragma unroll 2
  for (int kt = 0; kt < DM; kt++) {
    double av[8], bv[8];
    #pragma unroll
    for (int i = 0; i < 8; i++) av[i] = (double)xr[i][kt];
    #pragma unroll
    for (int j = 0; j < 8; j++) bv[j] = (double)wr[(size_t)kt * NP + 16 * j];
    #pragma unroll
    for (int i = 0; i < 8; i++)
      #pragma unroll
      for (int j = 0; j < 8; j++)
        acc[i][j] = fma(av[i], bv[j], acc[i][j]);
  }

  int head = n0 >> 7;
  #pragma unroll
  for (int j = 0; j < 8; j++) {
    int col = tn + 16 * j;                 // column within head (n0 is head-aligned)
    double bb = (double)bia[n0 + col];
    #pragma unroll
    for (int i = 0; i < 8; i++) {
      int m = m0 + g + 16 * i;
      float val = (float)(acc[i][j] + bb);
      size_t idx = ((size_t)head * SEQ + m) * 128 + col;
      out[idx]  = val;
      outb[idx] = (bf16)val;
    }
  }
}

// ---------------- V projection via bf16 MFMA, out row-major [2048][2048] ----
__global__ __launch_bounds__(256) void proj_v_mfma(
    const float* __restrict__ X, const float* __restrict__ W,
    const float* __restrict__ bia, float* __restrict__ out) {
  __shared__ alignas(16) bf16 As[128][40];  // [m][k] BK=32
  __shared__ alignas(16) bf16 Bs[128][40];  // [n][k]
  int ms = blockIdx.x * 128, ns = blockIdx.y * 128;
  int t = threadIdx.x, w = t >> 6, lane = t & 63, l15 = lane & 15, qd = lane >> 4;
  int wm = (w >> 1) * 64, wn = (w & 1) * 64;
  int amr = t >> 1, akb = (t & 1) * 16;
  int bkr = t >> 3, bnb = (t & 7) * 16;
  floatx4 acc[4][4];
  for (int i = 0; i < 4; i++)
    for (int j = 0; j < 4; j++) acc[i][j] = (floatx4){0.f, 0.f, 0.f, 0.f};

  for (int kt = 0; kt < DM; kt += 32) {
    floatx4 xa[4], wv[4];
    for (int u = 0; u < 4; u++)
      xa[u] = *(const floatx4*)(X + (size_t)(ms + amr) * DM + kt + akb + u * 4);
    for (int u = 0; u < 4; u++)
      wv[u] = *(const floatx4*)(W + (size_t)(kt + bkr) * NP + ns + bnb + u * 4);
    __syncthreads();
    {
      bf16x8 p0, p1;
      for (int j = 0; j < 4; j++) { p0[j] = (bf16)xa[0][j]; p0[4 + j] = (bf16)xa[1][j]; }
      for (int j = 0; j < 4; j++) { p1[j] = (bf16)xa[2][j]; p1[4 + j] = (bf16)xa[3][j]; }
      *(bf16x8*)&As[amr][akb]     = p0;
      *(bf16x8*)&As[amr][akb + 8] = p1;
    }
    for (int u = 0; u < 4; u++)
      for (int j = 0; j < 4; j++)
        Bs[bnb + u * 4 + j][bkr] = (bf16)wv[u][j];
    __syncthreads();
    bf16x8 af[4], bfr[4];
    for (int i = 0; i < 4; i++) af[i]  = *(const bf16x8*)&As[wm + i * 16 + l15][qd * 8];
    for (int j = 0; j < 4; j++) bfr[j] = *(const bf16x8*)&Bs[wn + j * 16 + l15][qd * 8];
    for (int i = 0; i < 4; i++)
      for (int j = 0; j < 4; j++)
        acc[i][j] = __builtin_amdgcn_mfma_f32_16x16x32_bf16(af[i], bfr[j], acc[i][j], 0, 0, 0);
  }
  for (int i = 0; i < 4; i++) {
    for (int j = 0; j < 4; j++) {
      int n = ns + wn + j * 16 + l15;
      float bb = bia[n];
      for (int r = 0; r < 4; r++) {
        int m = ms + wm + i * 16 + qd * 4 + r;
        out[(size_t)m * NP + n] = acc[i][j][r] + bb;
      }
    }
  }
}

// ------- approx scores (bf16 MFMA) from pre-cast Q/K, reg-held A-frags ------
// Candidate semantics identical to the round-2/4 PASS: phase 1 finds the
// per-row masked min of approx scores; phase 2 collects all t with
// approx <= min + MARGIN for exact fp64 rescoring.
__global__ __launch_bounds__(256) void scores_cand(
    const bf16* __restrict__ Qb, const bf16* __restrict__ Kb,
    const int* __restrict__ mask,
    unsigned* __restrict__ cand, int* __restrict__ gcount) {
  int h = blockIdx.x, s0 = blockIdx.y * 64;
  __shared__ int   msk[2048];
  __shared__ float lmin[64][4];
  __shared__ float fmin[64];
  int t = threadIdx.x, w = t >> 6, lane = t & 63, l15 = lane & 15, qd = lane >> 4;
  for (int i = t; i < 2048; i += 256) msk[i] = mask[i];
  const bf16* Qh = Qb + (size_t)h * SEQ * 128;
  const bf16* Kh = Kb + (size_t)h * SEQ * 128;

  bf16x8 af[4][4];   // [ksp][i] — loop-invariant Q fragments
  for (int ksp = 0; ksp < 4; ksp++)
    for (int i = 0; i < 4; i++)
      af[ksp][i] = *(const bf16x8*)(Qh + (size_t)(s0 + i * 16 + l15) * 128 + ksp * 32 + qd * 8);
  __syncthreads();

  float rmin[4][4];
  for (int i = 0; i < 4; i++)
    for (int r = 0; r < 4; r++) rmin[i][r] = INFINITY;

  // phase 1: per-row masked min of approx scores
  for (int tt = 0; tt < 32; tt++) {
    int t0 = tt * 64;
    floatx4 acc[4];
    for (int i = 0; i < 4; i++) acc[i] = (floatx4){0.f, 0.f, 0.f, 0.f};
    for (int ksp = 0; ksp < 4; ksp++) {
      bf16x8 bfr = *(const bf16x8*)(Kh + (size_t)(t0 + w * 16 + l15) * 128 + ksp * 32 + qd * 8);
      for (int i = 0; i < 4; i++)
        acc[i] = __builtin_amdgcn_mfma_f32_16x16x32_bf16(af[ksp][i], bfr, acc[i], 0, 0, 0);
    }
    bool okc = msk[t0 + w * 16 + l15] != 0;
    for (int i = 0; i < 4; i++)
      for (int r = 0; r < 4; r++)
        rmin[i][r] = fminf(rmin[i][r], okc ? acc[i][r] : INFINITY);
  }
  for (int m = 1; m < 16; m <<= 1)
    for (int i = 0; i < 4; i++)
      for (int r = 0; r < 4; r++)
        rmin[i][r] = fminf(rmin[i][r], __shfl_xor(rmin[i][r], m));
  if (l15 == 0)
    for (int i = 0; i < 4; i++)
      for (int r = 0; r < 4; r++)
        lmin[i * 16 + qd * 4 + r][w] = rmin[i][r];
  __syncthreads();
  if (t < 64)
    fmin[t] = fminf(fminf(lmin[t][0], lmin[t][1]), fminf(lmin[t][2], lmin[t][3])) + MARGIN;
  __syncthreads();

  // phase 2: collect candidates within MARGIN of the min
  for (int tt = 0; tt < 32; tt++) {
    int t0 = tt * 64;
    floatx4 acc[4];
    for (int i = 0; i < 4; i++) acc[i] = (floatx4){0.f, 0.f, 0.f, 0.f};
    for (int ksp = 0; ksp < 4; ksp++) {
      bf16x8 bfr = *(const bf16x8*)(Kh + (size_t)(t0 + w * 16 + l15) * 128 + ksp * 32 + qd * 8);
      for (int i = 0; i < 4; i++)
        acc[i] = __builtin_amdgcn_mfma_f32_16x16x32_bf16(af[ksp][i], bfr, acc[i], 0, 0, 0);
    }
    int tg = t0 + w * 16 + l15;
    if (msk[tg] != 0) {
      for (int i = 0; i < 4; i++)
        for (int r = 0; r < 4; r++) {
          int row = i * 16 + qd * 4 + r;
          if (acc[i][r] <= fmin[row] && msk[s0 + row]) {
            int pos = atomicAdd(gcount, 1);
            if (pos < CAP)
              cand[pos] = ((unsigned)h << 22) | ((unsigned)(s0 + row) << 11) | (unsigned)tg;
          }
        }
    }
  }
}

// ---------------- fp64 exact rescore of candidates, atomicMin key ----------
__global__ __launch_bounds__(256) void rescore(
    const float* __restrict__ Q, const float* __restrict__ K,
    const unsigned* __restrict__ cand, const int* __restrict__ gcount,
    unsigned long long* __restrict__ keys) {
  int wid  = (blockIdx.x * 256 + threadIdx.x) >> 6;
  int lane = threadIdx.x & 63;
  int nw = gridDim.x * 4;
  int n = *gcount; if (n > CAP) n = CAP;
  for (int c = wid; c < n; c += nw) {
    unsigned u = cand[c];
    int h = u >> 22, s = (u >> 11) & 2047, tt = u & 2047;
    floatx2 qv = *(const floatx2*)(Q + ((size_t)h * SEQ + s)  * 128 + lane * 2);
    floatx2 kv = *(const floatx2*)(K + ((size_t)h * SEQ + tt) * 128 + lane * 2);
    double d = (double)qv[0] * (double)kv[0] + (double)qv[1] * (double)kv[1];
    for (int off = 32; off; off >>= 1) d += __shfl_down(d, off);
    if (lane == 0) {
      long long b = __double_as_longlong(d);
      unsigned long long ub = (b >= 0) ? ((unsigned long long)b | 0x8000000000000000ULL)
                                       : ~(unsigned long long)b;
      unsigned long long key = (ub & ~2047ULL) | (unsigned long long)tt;
      atomicMin(&keys[(size_t)h * SEQ + s], key);
    }
  }
}

// ---------------- column sums of V ----------------
__global__ __launch_bounds__(256) void vmean_partial(const float* __restrict__ V,
                                                     float* __restrict__ sums) {
  int n  = blockIdx.x * 256 + threadIdx.x;
  int s0 = blockIdx.y * 64;
  float s = 0.f;
  for (int r = 0; r < 64; r++) s += V[(size_t)(s0 + r) * NP + n];
  atomicAdd(&sums[n], s);
}

// ---------------- gather / mean, fp32 out ----------------
__global__ __launch_bounds__(256) void assemble(
    const float* __restrict__ V, const float* __restrict__ sums,
    const int* __restrict__ mask, const unsigned long long* __restrict__ keys,
    float* __restrict__ out) {
  int idx = blockIdx.x * 256 + threadIdx.x;
  int s = idx >> 11, n = idx & 2047, h = n >> 7;
  float val;
  if (mask[s]) {
    int tt = (int)(keys[(size_t)h * SEQ + s] & 2047ULL);
    val = V[(size_t)tt * NP + n];
  } else {
    val = sums[n] * (1.0f / 2048.0f);
  }
  out[idx] = val;
}

extern "C" void kernel_launch(void* const* d_in, const int* in_sizes, int n_in,
                              void* d_out, int out_size, void* d_ws, size_t ws_size,
                              hipStream_t stream) {
  (void)in_sizes; (void)n_in; (void)out_size; (void)ws_size;
  const float* X    = (const float*)d_in[0];
  const void*  mraw = d_in[1];
  const float* Wq   = (const float*)d_in[2];
  const float* bq   = (const float*)d_in[3];
  const float* Wk   = (const float*)d_in[4];
  const float* bk   = (const float*)d_in[5];
  const float* Wv   = (const float*)d_in[6];
  const float* bv   = (const float*)d_in[7];

  char* ws = (char*)d_ws;
  float* qf = (float*)ws;                                   // 16MB [16][2048][128]
  float* kf = (float*)(ws + ((size_t)16 << 20));            // 16MB
  float* vf = (float*)(ws + ((size_t)32 << 20));            // 16MB [2048][2048]
  int*   maskw  = (int*)(ws + ((size_t)48 << 20));                    // 8KB
  int*   gcount = (int*)(ws + ((size_t)48 << 20) + (16 << 10));       // 4B
  float* sums   = (float*)(ws + ((size_t)48 << 20) + (32 << 10));     // 8KB
  unsigned long long* keys = (unsigned long long*)(ws + ((size_t)48 << 20) + (64 << 10)); // 256KB
  unsigned* cand = (unsigned*)(ws + ((size_t)49 << 20));    // 4MB @49
  bf16* qbf = (bf16*)(ws + ((size_t)53 << 20));             // 8MB  @53
  bf16* kbf = (bf16*)(ws + ((size_t)61 << 20));             // 8MB  @61
  float* out = (float*)d_out;

  mask_prep<<<1, 256, 0, stream>>>(mraw, maskw);
  hipMemsetAsync(gcount, 0, 4, stream);
  hipMemsetAsync(sums, 0, 2048 * sizeof(float), stream);
  hipMemsetAsync(keys, 0xFF, (size_t)16 * SEQ * 8, stream);
  proj_qk<<<dim3(16, 16, 2), 256, 0, stream>>>(X, Wq, Wk, bq, bk, qf, kf, qbf, kbf);
  proj_v_mfma<<<dim3(16, 16), 256, 0, stream>>>(X, Wv, bv, vf);
  scores_cand<<<dim3(16, 32), 256, 0, stream>>>(qbf, kbf, maskw, cand, gcount);
  rescore<<<1024, 256, 0, stream>>>(qf, kf, cand, gcount, keys);
  vmean_partial<<<dim3(8, 32), 256, 0, stream>>>(vf, sums);
  assemble<<<16384, 256, 0, stream>>>(vf, sums, maskw, keys, out);
}